// Round 1
// baseline (822.615 us; speedup 1.0000x reference)
//
#include <hip/hip_runtime.h>
#include <hip/hip_bf16.h>
#include <stdint.h>

#define FDIM   1024
#define NCLS   100
#define CDIM   512
#define NBATCH 4096

typedef __attribute__((ext_vector_type(8))) short short8;
typedef __attribute__((ext_vector_type(4))) float f32x4;

__device__ __forceinline__ unsigned short f2bf_bits(float f) {
    union { float f; uint32_t u; } v; v.f = f;
    uint32_t u = v.u;
    return (unsigned short)((u + 0x7FFFu + ((u >> 16) & 1u)) >> 16);
}

// ---- convert x: f32 [4096][1024] -> bf16 same layout ----
__global__ void cvt_x_kernel(const float* __restrict__ x, unsigned short* __restrict__ xb) {
    const int i = (blockIdx.x * 256 + threadIdx.x) * 8;   // exact: 2048 blocks * 2048 elems
    f32x4 a = *(const f32x4*)(x + i);
    f32x4 b = *(const f32x4*)(x + i + 4);
    short8 h;
#pragma unroll
    for (int e = 0; e < 4; ++e) { h[e] = (short)f2bf_bits(a[e]); h[e + 4] = (short)f2bf_bits(b[e]); }
    *(short8*)(xb + i) = h;
}

// ---- convert weight: f32 [m][n][j] -> bf16 [n][m][j] ----
__global__ void cvt_w_kernel(const float* __restrict__ w, unsigned short* __restrict__ wb) {
    const int mn = blockIdx.x;              // m*NCLS + n
    const int m = mn / NCLS, n = mn % NCLS;
    const float* src = w + (size_t)mn * FDIM;
    unsigned short* dst = wb + ((size_t)n * CDIM + m) * FDIM;
    const int c = threadIdx.x * 8;          // 128 threads * 8 = 1024
    f32x4 a = *(const f32x4*)(src + c);
    f32x4 b = *(const f32x4*)(src + c + 4);
    short8 h;
#pragma unroll
    for (int e = 0; e < 4; ++e) { h[e] = (short)f2bf_bits(a[e]); h[e + 4] = (short)f2bf_bits(b[e]); }
    *(short8*)(dst + c) = h;
}

// ---- fused DUQ kernel: per block = (class n, 128 batch rows) ----
// GEMM 128x128x1024 per m-chunk (4 chunks), epilogue accumulates (z-c)^2.
template<bool PRECONV>
__global__ __launch_bounds__(256, 2)
void duq_kernel(const float* __restrict__ x, const float* __restrict__ w,
                const unsigned short* __restrict__ xb, const unsigned short* __restrict__ wb,
                const float* __restrict__ csum, const float* __restrict__ cnum,
                float* __restrict__ out) {
    __shared__ unsigned short lsA[128 * 64];
    __shared__ unsigned short lsB[128 * 64];
    __shared__ float c_lds[CDIM];
    __shared__ float red[2][128];

    const int t    = threadIdx.x;
    const int n    = blockIdx.x >> 5;    // class 0..99 (32 consecutive blocks share W_n)
    const int tile = blockIdx.x & 31;    // batch tile 0..31
    const int lane = t & 63;
    const int wid  = t >> 6;
    const int wrow = wid >> 1;           // 0..1  (64 batch rows)
    const int wcol = wid & 1;            // 0..1  (64 m cols)
    const int ln15 = lane & 15;
    const int hi   = lane >> 4;          // 0..3

    // centroids for this class into LDS
    {
        const float inv = 1.0f / cnum[n];
        for (int m = t; m < CDIM; m += 256)
            c_lds[m] = csum[(size_t)m * NCLS + n] * inv;
    }

    // staging map: 4 passes of 32 rows; 8 threads per row, 8 elems (16B) each
    const int srow = t >> 3;             // 0..31
    const int scol = (t & 7) * 8;        // 0,8,...,56
    const int swz  = (srow & 7) << 4;    // XOR swizzle (G4)

    float p[16];
#pragma unroll
    for (int q = 0; q < 16; ++q) p[q] = 0.0f;

    for (int chunk = 0; chunk < 4; ++chunk) {
        f32x4 acc[4][4];
#pragma unroll
        for (int i = 0; i < 4; ++i)
#pragma unroll
            for (int j = 0; j < 4; ++j)
                acc[i][j] = f32x4{0.0f, 0.0f, 0.0f, 0.0f};

        for (int ks = 0; ks < 16; ++ks) {
            const int k = ks * 64;
            __syncthreads();
#pragma unroll
            for (int pp = 0; pp < 4; ++pp) {
                const int row = pp * 32 + srow;
                short8 ha, hb;
                if constexpr (PRECONV) {
                    ha = *(const short8*)(xb + ((size_t)(tile * 128 + row)) * FDIM + k + scol);
                    hb = *(const short8*)(wb + ((size_t)n * CDIM + chunk * 128 + row) * FDIM + k + scol);
                } else {
                    const float* pa = x + ((size_t)(tile * 128 + row)) * FDIM + k + scol;
                    const float* pb = w + ((size_t)(chunk * 128 + row) * NCLS + n) * FDIM + k + scol;
                    f32x4 a0 = *(const f32x4*)pa, a1 = *(const f32x4*)(pa + 4);
                    f32x4 b0 = *(const f32x4*)pb, b1 = *(const f32x4*)(pb + 4);
#pragma unroll
                    for (int e = 0; e < 4; ++e) {
                        ha[e]     = (short)f2bf_bits(a0[e]);
                        ha[e + 4] = (short)f2bf_bits(a1[e]);
                        hb[e]     = (short)f2bf_bits(b0[e]);
                        hb[e + 4] = (short)f2bf_bits(b1[e]);
                    }
                }
                const int byte = (row * 128 + scol * 2) ^ swz;
                *(short8*)((char*)lsA + byte) = ha;
                *(short8*)((char*)lsB + byte) = hb;
            }
            __syncthreads();
#pragma unroll
            for (int kk = 0; kk < 2; ++kk) {
                short8 af[4], bf[4];
#pragma unroll
                for (int i = 0; i < 4; ++i) {
                    const int rowA = wrow * 64 + i * 16 + ln15;
                    const int ba = (rowA * 128 + (kk * 32 + hi * 8) * 2) ^ ((rowA & 7) << 4);
                    af[i] = *(const short8*)((const char*)lsA + ba);
                    const int rowB = wcol * 64 + i * 16 + ln15;
                    const int bb = (rowB * 128 + (kk * 32 + hi * 8) * 2) ^ ((rowB & 7) << 4);
                    bf[i] = *(const short8*)((const char*)lsB + bb);
                }
#pragma unroll
                for (int i = 0; i < 4; ++i)
#pragma unroll
                    for (int j = 0; j < 4; ++j)
                        acc[i][j] = __builtin_amdgcn_mfma_f32_16x16x32_bf16(af[i], bf[j], acc[i][j], 0, 0, 0);
            }
        }

        // epilogue: (z - c)^2 accumulated per batch-row partials
#pragma unroll
        for (int i = 0; i < 4; ++i)
#pragma unroll
            for (int j = 0; j < 4; ++j) {
                const int m = chunk * 128 + wcol * 64 + j * 16 + ln15;
                const float c = c_lds[m];
#pragma unroll
                for (int r = 0; r < 4; ++r) {
                    const float d = acc[i][j][r] - c;
                    p[i * 4 + r] += d * d;
                }
            }
    }

    // reduce across the 16 lanes holding different m-columns
#pragma unroll
    for (int q = 0; q < 16; ++q) {
        float v = p[q];
        v += __shfl_xor(v, 1);
        v += __shfl_xor(v, 2);
        v += __shfl_xor(v, 4);
        v += __shfl_xor(v, 8);
        p[q] = v;
    }
    __syncthreads();
    if (ln15 == 0) {
#pragma unroll
        for (int i = 0; i < 4; ++i)
#pragma unroll
            for (int r = 0; r < 4; ++r)
                red[wcol][wrow * 64 + i * 16 + hi * 4 + r] = p[i * 4 + r];
    }
    __syncthreads();
    if (t < 128) {
        const float sq = (red[0][t] + red[1][t]) * (1.0f / 512.0f);
        const float lc = -50.0f * sq;                 // -sq / (2*0.1^2)
        const size_t b = (size_t)tile * 128 + t;
        out[b * NCLS + n] = expf(lc);                 // confidences
        out[(size_t)NBATCH * NCLS + b * NCLS + n] = lc; // log_confidences
    }
}

extern "C" void kernel_launch(void* const* d_in, const int* in_sizes, int n_in,
                              void* d_out, int out_size, void* d_ws, size_t ws_size,
                              hipStream_t stream) {
    const float* x    = (const float*)d_in[0];
    const float* w    = (const float*)d_in[1];
    const float* csum = (const float*)d_in[2];
    const float* cnum = (const float*)d_in[3];
    float* out = (float*)d_out;

    const size_t need = ((size_t)NBATCH * FDIM + (size_t)CDIM * NCLS * FDIM) * sizeof(unsigned short);
    const dim3 grid(NCLS * 32), block(256);

    if (ws_size >= need) {
        unsigned short* xb = (unsigned short*)d_ws;
        unsigned short* wb = xb + (size_t)NBATCH * FDIM;
        cvt_x_kernel<<<dim3((NBATCH * FDIM) / 2048), dim3(256), 0, stream>>>(x, xb);
        cvt_w_kernel<<<dim3(CDIM * NCLS), dim3(128), 0, stream>>>(w, wb);
        duq_kernel<true><<<grid, block, 0, stream>>>(x, w, xb, wb, csum, cnum, out);
    } else {
        duq_kernel<false><<<grid, block, 0, stream>>>(x, w, nullptr, nullptr, csum, cnum, out);
    }
}

// Round 2
// 785.320 us; speedup vs baseline: 1.0475x; 1.0475x over previous
//
#include <hip/hip_runtime.h>
#include <hip/hip_bf16.h>
#include <stdint.h>

#define FDIM   1024
#define NCLS   100
#define CDIM   512
#define NBATCH 4096

typedef __attribute__((ext_vector_type(8))) short short8;
typedef __attribute__((ext_vector_type(4))) float f32x4;

typedef const __attribute__((address_space(1))) unsigned int guint;
typedef __attribute__((address_space(3))) unsigned int luint;

__device__ __forceinline__ void gl_lds16(const unsigned short* g, void* l) {
    __builtin_amdgcn_global_load_lds((guint*)g, (luint*)l, 16, 0, 0);
}

__device__ __forceinline__ unsigned short f2bf_bits(float f) {
    union { float f; uint32_t u; } v; v.f = f;
    uint32_t u = v.u;
    return (unsigned short)((u + 0x7FFFu + ((u >> 16) & 1u)) >> 16);
}

// ---- convert x: f32 [4096][1024] -> bf16 same layout ----
__global__ void cvt_x_kernel(const float* __restrict__ x, unsigned short* __restrict__ xb) {
    const int i = (blockIdx.x * 256 + threadIdx.x) * 8;
    f32x4 a = *(const f32x4*)(x + i);
    f32x4 b = *(const f32x4*)(x + i + 4);
    short8 h;
#pragma unroll
    for (int e = 0; e < 4; ++e) { h[e] = (short)f2bf_bits(a[e]); h[e + 4] = (short)f2bf_bits(b[e]); }
    *(short8*)(xb + i) = h;
}

// ---- convert weight: f32 [m][n][j] -> bf16 [n][m][j] ----
__global__ void cvt_w_kernel(const float* __restrict__ w, unsigned short* __restrict__ wb) {
    const int mn = blockIdx.x;              // m*NCLS + n
    const int m = mn / NCLS, n = mn % NCLS;
    const float* src = w + (size_t)mn * FDIM;
    unsigned short* dst = wb + ((size_t)n * CDIM + m) * FDIM;
    const int c = threadIdx.x * 8;
    f32x4 a = *(const f32x4*)(src + c);
    f32x4 b = *(const f32x4*)(src + c + 4);
    short8 h;
#pragma unroll
    for (int e = 0; e < 4; ++e) { h[e] = (short)f2bf_bits(a[e]); h[e + 4] = (short)f2bf_bits(b[e]); }
    *(short8*)(dst + c) = h;
}

// ---- fused DUQ, m97-structure: global_load_lds(16B) + pre-swizzled source ----
// block = (class n, 128 batch rows); 4 m-chunks of 128; BK=64; 4 waves 2x2.
__global__ __launch_bounds__(256, 2)
void duq_gll(const unsigned short* __restrict__ xb, const unsigned short* __restrict__ wb,
             const float* __restrict__ csum, const float* __restrict__ cnum,
             float* __restrict__ out) {
    __shared__ unsigned short lsA[128 * 64];
    __shared__ unsigned short lsB[128 * 64];
    __shared__ float c_lds[CDIM];
    __shared__ float red[2][128];

    const int t = threadIdx.x;
    // bijective XCD swizzle: nwg=3200, 3200%8==0 -> each XCD gets 400 contiguous
    // logical blocks = 12.5 classes; resident weight slice ~4MB = one L2.
    const int logical = (blockIdx.x & 7) * 400 + (blockIdx.x >> 3);
    const int n    = logical >> 5;       // class 0..99
    const int tile = logical & 31;       // batch tile 0..31
    const int lane = t & 63;
    const int wid  = t >> 6;
    const int wrow = wid >> 1;           // 0..1 (batch 64-row half)
    const int wcol = wid & 1;            // 0..1 (m 64-col half)
    const int ln15 = lane & 15;
    const int hi   = lane >> 4;

    {
        const float inv = 1.0f / cnum[n];
        for (int m = t; m < CDIM; m += 256)
            c_lds[m] = csum[(size_t)m * NCLS + n] * inv;
    }

    // staging geometry: wave wid covers rows [wid*32, wid*32+32) in 4 gl_lds of 1KB.
    // LDS dest is LINEAR (o = wid*4096 + i*1024 + lane*16); the XOR swizzle
    // lds[(row*128+cb) ^ ((row&7)<<4)] = data[row][cb/2] is realized by permuting
    // the GLOBAL source column block: row&7 == lane>>3, cb_src = (lane&7)^(lane>>3).
    const int rsub  = lane >> 3;                       // 0..7
    const int cbs   = ((lane & 7) ^ rsub) * 8;         // source col element
    const int rbase = wid * 32 + rsub;                 // + i*8
    const unsigned short* gA = xb + (size_t)(tile * 128 + rbase) * FDIM + cbs;
    char* ldA = (char*)lsA + wid * 4096;
    char* ldB = (char*)lsB + wid * 4096;

    float p[16];
#pragma unroll
    for (int q = 0; q < 16; ++q) p[q] = 0.0f;

    for (int chunk = 0; chunk < 4; ++chunk) {
        const unsigned short* gB = wb + ((size_t)n * CDIM + chunk * 128 + rbase) * FDIM + cbs;
        f32x4 acc[4][4];
#pragma unroll
        for (int i = 0; i < 4; ++i)
#pragma unroll
            for (int j = 0; j < 4; ++j)
                acc[i][j] = f32x4{0.0f, 0.0f, 0.0f, 0.0f};

        for (int ks = 0; ks < 16; ++ks) {
            const int k = ks * 64;
            __syncthreads();                       // prev compute done before overwrite
#pragma unroll
            for (int i = 0; i < 4; ++i) {
                gl_lds16(gA + (size_t)i * 8 * FDIM + k, ldA + i * 1024);
                gl_lds16(gB + (size_t)i * 8 * FDIM + k, ldB + i * 1024);
            }
            __syncthreads();                       // drains vmcnt -> tiles ready
#pragma unroll
            for (int kk = 0; kk < 2; ++kk) {
                short8 af[4], bf[4];
#pragma unroll
                for (int i = 0; i < 4; ++i) {
                    const int rowA = wrow * 64 + i * 16 + ln15;
                    const int ba = (rowA * 128 + (kk * 32 + hi * 8) * 2) ^ ((rowA & 7) << 4);
                    af[i] = *(const short8*)((const char*)lsA + ba);
                    const int rowB = wcol * 64 + i * 16 + ln15;
                    const int bb = (rowB * 128 + (kk * 32 + hi * 8) * 2) ^ ((rowB & 7) << 4);
                    bf[i] = *(const short8*)((const char*)lsB + bb);
                }
#pragma unroll
                for (int i = 0; i < 4; ++i)
#pragma unroll
                    for (int j = 0; j < 4; ++j)
                        acc[i][j] = __builtin_amdgcn_mfma_f32_16x16x32_bf16(af[i], bf[j], acc[i][j], 0, 0, 0);
            }
        }

#pragma unroll
        for (int i = 0; i < 4; ++i)
#pragma unroll
            for (int j = 0; j < 4; ++j) {
                const int m = chunk * 128 + wcol * 64 + j * 16 + ln15;
                const float c = c_lds[m];
#pragma unroll
                for (int r = 0; r < 4; ++r) {
                    const float d = acc[i][j][r] - c;
                    p[i * 4 + r] += d * d;
                }
            }
    }

#pragma unroll
    for (int q = 0; q < 16; ++q) {
        float v = p[q];
        v += __shfl_xor(v, 1);
        v += __shfl_xor(v, 2);
        v += __shfl_xor(v, 4);
        v += __shfl_xor(v, 8);
        p[q] = v;
    }
    __syncthreads();
    if (ln15 == 0) {
#pragma unroll
        for (int i = 0; i < 4; ++i)
#pragma unroll
            for (int r = 0; r < 4; ++r)
                red[wcol][wrow * 64 + i * 16 + hi * 4 + r] = p[i * 4 + r];
    }
    __syncthreads();
    if (t < 128) {
        const float sq = (red[0][t] + red[1][t]) * (1.0f / 512.0f);
        const float lc = -50.0f * sq;
        const size_t b = (size_t)tile * 128 + t;
        out[b * NCLS + n] = expf(lc);
        out[(size_t)NBATCH * NCLS + b * NCLS + n] = lc;
    }
}

// ---- fallback (no workspace): round-0 reg-staged inline-convert variant ----
__global__ __launch_bounds__(256, 2)
void duq_fallback(const float* __restrict__ x, const float* __restrict__ w,
                  const float* __restrict__ csum, const float* __restrict__ cnum,
                  float* __restrict__ out) {
    __shared__ unsigned short lsA[128 * 64];
    __shared__ unsigned short lsB[128 * 64];
    __shared__ float c_lds[CDIM];
    __shared__ float red[2][128];

    const int t = threadIdx.x;
    const int n    = blockIdx.x >> 5;
    const int tile = blockIdx.x & 31;
    const int lane = t & 63;
    const int wid  = t >> 6;
    const int wrow = wid >> 1;
    const int wcol = wid & 1;
    const int ln15 = lane & 15;
    const int hi   = lane >> 4;

    {
        const float inv = 1.0f / cnum[n];
        for (int m = t; m < CDIM; m += 256)
            c_lds[m] = csum[(size_t)m * NCLS + n] * inv;
    }

    const int srow = t >> 3;
    const int scol = (t & 7) * 8;
    const int swz  = (srow & 7) << 4;

    float p[16];
#pragma unroll
    for (int q = 0; q < 16; ++q) p[q] = 0.0f;

    for (int chunk = 0; chunk < 4; ++chunk) {
        f32x4 acc[4][4];
#pragma unroll
        for (int i = 0; i < 4; ++i)
#pragma unroll
            for (int j = 0; j < 4; ++j)
                acc[i][j] = f32x4{0.0f, 0.0f, 0.0f, 0.0f};

        for (int ks = 0; ks < 16; ++ks) {
            const int k = ks * 64;
            __syncthreads();
#pragma unroll
            for (int pp = 0; pp < 4; ++pp) {
                const int row = pp * 32 + srow;
                const float* pa = x + ((size_t)(tile * 128 + row)) * FDIM + k + scol;
                const float* pb = w + ((size_t)(chunk * 128 + row) * NCLS + n) * FDIM + k + scol;
                f32x4 a0 = *(const f32x4*)pa, a1 = *(const f32x4*)(pa + 4);
                f32x4 b0 = *(const f32x4*)pb, b1 = *(const f32x4*)(pb + 4);
                short8 ha, hb;
#pragma unroll
                for (int e = 0; e < 4; ++e) {
                    ha[e] = (short)f2bf_bits(a0[e]); ha[e + 4] = (short)f2bf_bits(a1[e]);
                    hb[e] = (short)f2bf_bits(b0[e]); hb[e + 4] = (short)f2bf_bits(b1[e]);
                }
                const int byte = (row * 128 + scol * 2) ^ swz;
                *(short8*)((char*)lsA + byte) = ha;
                *(short8*)((char*)lsB + byte) = hb;
            }
            __syncthreads();
#pragma unroll
            for (int kk = 0; kk < 2; ++kk) {
                short8 af[4], bf[4];
#pragma unroll
                for (int i = 0; i < 4; ++i) {
                    const int rowA = wrow * 64 + i * 16 + ln15;
                    const int ba = (rowA * 128 + (kk * 32 + hi * 8) * 2) ^ ((rowA & 7) << 4);
                    af[i] = *(const short8*)((const char*)lsA + ba);
                    const int rowB = wcol * 64 + i * 16 + ln15;
                    const int bb = (rowB * 128 + (kk * 32 + hi * 8) * 2) ^ ((rowB & 7) << 4);
                    bf[i] = *(const short8*)((const char*)lsB + bb);
                }
#pragma unroll
                for (int i = 0; i < 4; ++i)
#pragma unroll
                    for (int j = 0; j < 4; ++j)
                        acc[i][j] = __builtin_amdgcn_mfma_f32_16x16x32_bf16(af[i], bf[j], acc[i][j], 0, 0, 0);
            }
        }

#pragma unroll
        for (int i = 0; i < 4; ++i)
#pragma unroll
            for (int j = 0; j < 4; ++j) {
                const int m = chunk * 128 + wcol * 64 + j * 16 + ln15;
                const float c = c_lds[m];
#pragma unroll
                for (int r = 0; r < 4; ++r) {
                    const float d = acc[i][j][r] - c;
                    p[i * 4 + r] += d * d;
                }
            }
    }

#pragma unroll
    for (int q = 0; q < 16; ++q) {
        float v = p[q];
        v += __shfl_xor(v, 1);
        v += __shfl_xor(v, 2);
        v += __shfl_xor(v, 4);
        v += __shfl_xor(v, 8);
        p[q] = v;
    }
    __syncthreads();
    if (ln15 == 0) {
#pragma unroll
        for (int i = 0; i < 4; ++i)
#pragma unroll
            for (int r = 0; r < 4; ++r)
                red[wcol][wrow * 64 + i * 16 + hi * 4 + r] = p[i * 4 + r];
    }
    __syncthreads();
    if (t < 128) {
        const float sq = (red[0][t] + red[1][t]) * (1.0f / 512.0f);
        const float lc = -50.0f * sq;
        const size_t b = (size_t)tile * 128 + t;
        out[b * NCLS + n] = expf(lc);
        out[(size_t)NBATCH * NCLS + b * NCLS + n] = lc;
    }
}

extern "C" void kernel_launch(void* const* d_in, const int* in_sizes, int n_in,
                              void* d_out, int out_size, void* d_ws, size_t ws_size,
                              hipStream_t stream) {
    const float* x    = (const float*)d_in[0];
    const float* w    = (const float*)d_in[1];
    const float* csum = (const float*)d_in[2];
    const float* cnum = (const float*)d_in[3];
    float* out = (float*)d_out;

    const size_t need = ((size_t)NBATCH * FDIM + (size_t)CDIM * NCLS * FDIM) * sizeof(unsigned short);
    const dim3 grid(NCLS * 32), block(256);

    if (ws_size >= need) {
        unsigned short* xb = (unsigned short*)d_ws;
        unsigned short* wb = xb + (size_t)NBATCH * FDIM;
        cvt_x_kernel<<<dim3((NBATCH * FDIM) / 2048), dim3(256), 0, stream>>>(x, xb);
        cvt_w_kernel<<<dim3(CDIM * NCLS), dim3(128), 0, stream>>>(w, wb);
        duq_gll<<<grid, block, 0, stream>>>(xb, wb, csum, cnum, out);
    } else {
        duq_fallback<<<grid, block, 0, stream>>>(x, w, csum, cnum, out);
    }
}

// Round 3
// 544.340 us; speedup vs baseline: 1.5112x; 1.4427x over previous
//
#include <hip/hip_runtime.h>
#include <hip/hip_bf16.h>
#include <stdint.h>

#define FDIM   1024
#define NCLS   100
#define CDIM   512
#define NBATCH 4096

typedef __attribute__((ext_vector_type(8))) short short8;
typedef __attribute__((ext_vector_type(4))) float f32x4;

typedef const __attribute__((address_space(1))) unsigned int guint;
typedef __attribute__((address_space(3))) unsigned int luint;

__device__ __forceinline__ void gl_lds16(const unsigned short* g, unsigned short* l) {
    __builtin_amdgcn_global_load_lds((guint*)g, (luint*)l, 16, 0, 0);
}

__device__ __forceinline__ unsigned short f2bf_bits(float f) {
    union { float f; uint32_t u; } v; v.f = f;
    uint32_t u = v.u;
    return (unsigned short)((u + 0x7FFFu + ((u >> 16) & 1u)) >> 16);
}

// ---- convert x: f32 [4096][1024] -> bf16 same layout ----
__global__ void cvt_x_kernel(const float* __restrict__ x, unsigned short* __restrict__ xb) {
    const int i = (blockIdx.x * 256 + threadIdx.x) * 8;
    f32x4 a = *(const f32x4*)(x + i);
    f32x4 b = *(const f32x4*)(x + i + 4);
    short8 h;
#pragma unroll
    for (int e = 0; e < 4; ++e) { h[e] = (short)f2bf_bits(a[e]); h[e + 4] = (short)f2bf_bits(b[e]); }
    *(short8*)(xb + i) = h;
}

// ---- convert weight: f32 [m][n][j] -> bf16 [n][m][j] ----
__global__ void cvt_w_kernel(const float* __restrict__ w, unsigned short* __restrict__ wb) {
    const int mn = blockIdx.x;              // m*NCLS + n
    const int m = mn / NCLS, n = mn % NCLS;
    const float* src = w + (size_t)mn * FDIM;
    unsigned short* dst = wb + ((size_t)n * CDIM + m) * FDIM;
    const int c = threadIdx.x * 8;
    f32x4 a = *(const f32x4*)(src + c);
    f32x4 b = *(const f32x4*)(src + c + 4);
    short8 h;
#pragma unroll
    for (int e = 0; e < 4; ++e) { h[e] = (short)f2bf_bits(a[e]); h[e + 4] = (short)f2bf_bits(b[e]); }
    *(short8*)(dst + c) = h;
}

// ---- fused DUQ, 256x256x64 deep-pipelined structure ----
// block = (class n, 256 batch rows); loops 2 m-panels of 256; 8 waves (2Mx4N).
// Per K-tile: burst-stage next tile into other buffer (8x gl_lds, pre-swizzled
// source), 4 quadrant phases of {ds_read frags + 16 MFMA w/ setprio}, single
// __syncthreads (implicit vmcnt(0) with ~4 phases of cover).
__global__ __launch_bounds__(512, 2)
void duq8(const unsigned short* __restrict__ xb, const unsigned short* __restrict__ wb,
          const float* __restrict__ csum, const float* __restrict__ cnum,
          float* __restrict__ out) {
    __shared__ unsigned short lsA[2][256 * 64];   // 2 x 32 KB
    __shared__ unsigned short lsB[2][256 * 64];   // 2 x 32 KB
    __shared__ float c_lds[CDIM];
    __shared__ float red[4][256];

    const int t    = threadIdx.x;
    const int bid  = blockIdx.x;     // natural order (XCD swizzle reverted: r2 fetch 2.4x worse)
    const int n    = bid >> 4;       // class 0..99
    const int rt   = bid & 15;       // 256-row batch tile 0..15
    const int lane = t & 63;
    const int wid  = t >> 6;         // 0..7
    const int wm   = wid >> 2;       // 0..1 : rows wm*128..+127
    const int wn   = wid & 3;        // 0..3 : cols wn*64..+63
    const int ln15 = lane & 15;
    const int hi   = lane >> 4;

    // centroids for this class
    {
        const float inv = 1.0f / cnum[n];
        for (int m = t; m < CDIM; m += 512)
            c_lds[m] = csum[(size_t)m * NCLS + n] * inv;
    }

    // staging geometry: thread t covers row chunk*64 + (t>>3), 16B at source
    // column ((t&7) ^ (t>>3 & 7))*8  (pre-swizzled so linear LDS dest + XOR read
    // gives conflict-free ds_read_b128 — verified 0 conflicts in r1/r2).
    const int st_r = t >> 3;                       // 0..63
    const int st_c = ((t & 7) ^ (st_r & 7)) * 8;
    const unsigned short* gA = xb + ((size_t)(rt * 256 + st_r)) * FDIM + st_c;
    const unsigned short* gB = wb + ((size_t)n * CDIM + st_r) * FDIM + st_c;

    auto stage = [&](int it_, int bsel_) {
        const int k_  = (it_ & 15) * 64;
        const int pn_ = it_ >> 4;
#pragma unroll
        for (int c = 0; c < 4; ++c) {
            gl_lds16(gA + (size_t)(c * 64) * FDIM + k_,
                     &lsA[bsel_][c * 4096 + wid * 512]);
            gl_lds16(gB + ((size_t)(pn_ * 256 + c * 64)) * FDIM + k_,
                     &lsB[bsel_][c * 4096 + wid * 512]);
        }
    };

    f32x4 acc[8][4];
#pragma unroll
    for (int i = 0; i < 8; ++i)
#pragma unroll
        for (int j = 0; j < 4; ++j) acc[i][j] = f32x4{0.0f, 0.0f, 0.0f, 0.0f};

    stage(0, 0);
    __syncthreads();                 // drains this wave's gl_lds; barrier => tile 0 complete

    for (int it = 0; it < 32; ++it) {
        const int bs = it & 1;
        if (it + 1 < 32) stage(it + 1, bs ^ 1);   // into other buffer: safe, prev readers passed last barrier

        short8 af[2][4][2];          // [qr][i][kk], loaded at qc==0
        short8 bf[2][2][2];          // [qc][j][kk], loaded at qr==0
#pragma unroll
        for (int qr = 0; qr < 2; ++qr) {
#pragma unroll
            for (int qc = 0; qc < 2; ++qc) {
                if (qc == 0) {
#pragma unroll
                    for (int i = 0; i < 4; ++i) {
                        const int rowA = wm * 128 + (qr * 4 + i) * 16 + ln15;
#pragma unroll
                        for (int kk = 0; kk < 2; ++kk) {
                            const int ba = (rowA * 128 + (kk * 32 + hi * 8) * 2) ^ ((rowA & 7) << 4);
                            af[qr][i][kk] = *(const short8*)((const char*)lsA[bs] + ba);
                        }
                    }
                }
                if (qr == 0) {
#pragma unroll
                    for (int j = 0; j < 2; ++j) {
                        const int rowB = wn * 64 + (qc * 2 + j) * 16 + ln15;
#pragma unroll
                        for (int kk = 0; kk < 2; ++kk) {
                            const int bb = (rowB * 128 + (kk * 32 + hi * 8) * 2) ^ ((rowB & 7) << 4);
                            bf[qc][j][kk] = *(const short8*)((const char*)lsB[bs] + bb);
                        }
                    }
                }
                __builtin_amdgcn_s_setprio(1);
#pragma unroll
                for (int i = 0; i < 4; ++i)
#pragma unroll
                    for (int j = 0; j < 2; ++j)
#pragma unroll
                        for (int kk = 0; kk < 2; ++kk)
                            acc[qr * 4 + i][qc * 2 + j] =
                                __builtin_amdgcn_mfma_f32_16x16x32_bf16(
                                    af[qr][i][kk], bf[qc][j][kk],
                                    acc[qr * 4 + i][qc * 2 + j], 0, 0, 0);
                __builtin_amdgcn_s_setprio(0);
            }
        }
        __syncthreads();             // per-wave vmcnt(0) drain (covered) + all readers done with buf bs

        if ((it & 15) == 15) {       // end of a 256-col panel: fold (z-c)^2 into red
            const int pn = it >> 4;
            float p[8][4];
#pragma unroll
            for (int i = 0; i < 8; ++i)
#pragma unroll
                for (int r = 0; r < 4; ++r) p[i][r] = 0.0f;
#pragma unroll
            for (int i = 0; i < 8; ++i)
#pragma unroll
                for (int j = 0; j < 4; ++j) {
                    const int m = pn * 256 + wn * 64 + j * 16 + ln15;
                    const float c = c_lds[m];
#pragma unroll
                    for (int r = 0; r < 4; ++r) {
                        const float d = acc[i][j][r] - c;
                        p[i][r] += d * d;
                        acc[i][j][r] = 0.0f;          // reset for next panel
                    }
                }
#pragma unroll
            for (int i = 0; i < 8; ++i)
#pragma unroll
                for (int r = 0; r < 4; ++r) {
                    float v = p[i][r];
                    v += __shfl_xor(v, 1);
                    v += __shfl_xor(v, 2);
                    v += __shfl_xor(v, 4);
                    v += __shfl_xor(v, 8);
                    p[i][r] = v;
                }
            if (ln15 == 0) {
#pragma unroll
                for (int i = 0; i < 8; ++i)
#pragma unroll
                    for (int r = 0; r < 4; ++r) {
                        const int row = wm * 128 + i * 16 + hi * 4 + r;
                        if (pn == 0) red[wn][row] = p[i][r];
                        else         red[wn][row] += p[i][r];
                    }
            }
        }
    }

    __syncthreads();
    if (t < 256) {
        const float sq = (red[0][t] + red[1][t] + red[2][t] + red[3][t]) * (1.0f / 512.0f);
        const float lc = -50.0f * sq;                    // -sq / (2*0.1^2)
        const size_t b = (size_t)rt * 256 + t;
        out[b * NCLS + n] = expf(lc);
        out[(size_t)NBATCH * NCLS + b * NCLS + n] = lc;
    }
}

// ---- fallback (no workspace): reg-staged inline-convert variant (r1, verified) ----
__global__ __launch_bounds__(256, 2)
void duq_fallback(const float* __restrict__ x, const float* __restrict__ w,
                  const float* __restrict__ csum, const float* __restrict__ cnum,
                  float* __restrict__ out) {
    __shared__ unsigned short lsA[128 * 64];
    __shared__ unsigned short lsB[128 * 64];
    __shared__ float c_lds[CDIM];
    __shared__ float red[2][128];

    const int t = threadIdx.x;
    const int n    = blockIdx.x >> 5;
    const int tile = blockIdx.x & 31;
    const int lane = t & 63;
    const int wid  = t >> 6;
    const int wrow = wid >> 1;
    const int wcol = wid & 1;
    const int ln15 = lane & 15;
    const int hi   = lane >> 4;

    {
        const float inv = 1.0f / cnum[n];
        for (int m = t; m < CDIM; m += 256)
            c_lds[m] = csum[(size_t)m * NCLS + n] * inv;
    }

    const int srow = t >> 3;
    const int scol = (t & 7) * 8;
    const int swz  = (srow & 7) << 4;

    float p[16];
#pragma unroll
    for (int q = 0; q < 16; ++q) p[q] = 0.0f;

    for (int chunk = 0; chunk < 4; ++chunk) {
        f32x4 acc[4][4];
#pragma unroll
        for (int i = 0; i < 4; ++i)
#pragma unroll
            for (int j = 0; j < 4; ++j)
                acc[i][j] = f32x4{0.0f, 0.0f, 0.0f, 0.0f};

        for (int ks = 0; ks < 16; ++ks) {
            const int k = ks * 64;
            __syncthreads();
#pragma unroll
            for (int pp = 0; pp < 4; ++pp) {
                const int row = pp * 32 + srow;
                const float* pa = x + ((size_t)(tile * 128 + row)) * FDIM + k + scol;
                const float* pb = w + ((size_t)(chunk * 128 + row) * NCLS + n) * FDIM + k + scol;
                f32x4 a0 = *(const f32x4*)pa, a1 = *(const f32x4*)(pa + 4);
                f32x4 b0 = *(const f32x4*)pb, b1 = *(const f32x4*)(pb + 4);
                short8 ha, hb;
#pragma unroll
                for (int e = 0; e < 4; ++e) {
                    ha[e] = (short)f2bf_bits(a0[e]); ha[e + 4] = (short)f2bf_bits(a1[e]);
                    hb[e] = (short)f2bf_bits(b0[e]); hb[e + 4] = (short)f2bf_bits(b1[e]);
                }
                const int byte = (row * 128 + scol * 2) ^ swz;
                *(short8*)((char*)lsA + byte) = ha;
                *(short8*)((char*)lsB + byte) = hb;
            }
            __syncthreads();
#pragma unroll
            for (int kk = 0; kk < 2; ++kk) {
                short8 af[4], bfr[4];
#pragma unroll
                for (int i = 0; i < 4; ++i) {
                    const int rowA = wrow * 64 + i * 16 + ln15;
                    const int ba = (rowA * 128 + (kk * 32 + hi * 8) * 2) ^ ((rowA & 7) << 4);
                    af[i] = *(const short8*)((const char*)lsA + ba);
                    const int rowB = wcol * 64 + i * 16 + ln15;
                    const int bb = (rowB * 128 + (kk * 32 + hi * 8) * 2) ^ ((rowB & 7) << 4);
                    bfr[i] = *(const short8*)((const char*)lsB + bb);
                }
#pragma unroll
                for (int i = 0; i < 4; ++i)
#pragma unroll
                    for (int j = 0; j < 4; ++j)
                        acc[i][j] = __builtin_amdgcn_mfma_f32_16x16x32_bf16(af[i], bfr[j], acc[i][j], 0, 0, 0);
            }
        }

#pragma unroll
        for (int i = 0; i < 4; ++i)
#pragma unroll
            for (int j = 0; j < 4; ++j) {
                const int m = chunk * 128 + wcol * 64 + j * 16 + ln15;
                const float c = c_lds[m];
#pragma unroll
                for (int r = 0; r < 4; ++r) {
                    const float d = acc[i][j][r] - c;
                    p[i * 4 + r] += d * d;
                }
            }
    }

#pragma unroll
    for (int q = 0; q < 16; ++q) {
        float v = p[q];
        v += __shfl_xor(v, 1);
        v += __shfl_xor(v, 2);
        v += __shfl_xor(v, 4);
        v += __shfl_xor(v, 8);
        p[q] = v;
    }
    __syncthreads();
    if (ln15 == 0) {
#pragma unroll
        for (int i = 0; i < 4; ++i)
#pragma unroll
            for (int r = 0; r < 4; ++r)
                red[wcol][wrow * 64 + i * 16 + hi * 4 + r] = p[i * 4 + r];
    }
    __syncthreads();
    if (t < 128) {
        const float sq = (red[0][t] + red[1][t]) * (1.0f / 512.0f);
        const float lc = -50.0f * sq;
        const size_t b = (size_t)tile * 128 + t;
        out[b * NCLS + n] = expf(lc);
        out[(size_t)NBATCH * NCLS + b * NCLS + n] = lc;
    }
}

extern "C" void kernel_launch(void* const* d_in, const int* in_sizes, int n_in,
                              void* d_out, int out_size, void* d_ws, size_t ws_size,
                              hipStream_t stream) {
    const float* x    = (const float*)d_in[0];
    const float* w    = (const float*)d_in[1];
    const float* csum = (const float*)d_in[2];
    const float* cnum = (const float*)d_in[3];
    float* out = (float*)d_out;

    const size_t need = ((size_t)NBATCH * FDIM + (size_t)CDIM * NCLS * FDIM) * sizeof(unsigned short);

    if (ws_size >= need) {
        unsigned short* xb = (unsigned short*)d_ws;
        unsigned short* wb = xb + (size_t)NBATCH * FDIM;
        cvt_x_kernel<<<dim3((NBATCH * FDIM) / 2048), dim3(256), 0, stream>>>(x, xb);
        cvt_w_kernel<<<dim3(CDIM * NCLS), dim3(128), 0, stream>>>(w, wb);
        duq8<<<dim3(NCLS * 16), dim3(512), 0, stream>>>(xb, wb, csum, cnum, out);
    } else {
        duq_fallback<<<dim3(NCLS * 32), dim3(256), 0, stream>>>(x, w, csum, cnum, out);
    }
}